// Round 13
// baseline (275.280 us; speedup 1.0000x reference)
//
#include <hip/hip_runtime.h>
#include <hip/hip_bf16.h>

typedef __attribute__((ext_vector_type(8))) short short8;
typedef __attribute__((ext_vector_type(4))) float f32x4;

#define B_T 200
#define B_D 128

static __device__ __forceinline__ short f2bf(float f) {
  // round-to-nearest-even f32 -> bf16 (inputs are finite)
  unsigned u = __builtin_bit_cast(unsigned, f);
  u += 0x7fffu + ((u >> 16) & 1u);
  return (short)(u >> 16);
}
static __device__ __forceinline__ float bf2f(short s) {
  unsigned u = ((unsigned)(unsigned short)s) << 16;
  return __builtin_bit_cast(float, u);
}
static __device__ __forceinline__ short8 cvt8(f32x4 a, f32x4 b) {
  short8 t;
  t[0] = f2bf(a[0]); t[1] = f2bf(a[1]); t[2] = f2bf(a[2]); t[3] = f2bf(a[3]);
  t[4] = f2bf(b[0]); t[5] = f2bf(b[1]); t[6] = f2bf(b[2]); t[7] = f2bf(b[3]);
  return t;
}

// ---- prep 1: W1a/W1c -> fragment-linear bf16 tables (block-invariant, once).
__global__ __launch_bounds__(256) void ta_prep_w(const float* __restrict__ W1,
                                                 short* __restrict__ wfrag) {
  const int o = blockIdx.x * 256 + threadIdx.x;   // 2048 octets
  const int j = o & 127, k0 = (o >> 7) * 8;
  short8 ta, tc;
  #pragma unroll
  for (int e = 0; e < 8; ++e) {
    ta[e] = f2bf(W1[(size_t)(k0 + e) * B_D + j]);
    tc[e] = f2bf(W1[(size_t)(256 + k0 + e) * B_D + j]);
  }
  *(short8*)&wfrag[o * 8] = ta;
  *(short8*)&wfrag[16384 + o * 8] = tc;
}

// ---- prep 2: beta[b][j] = b1[j] + sum_k c[b][k]*W1b[k][j] (W1b LDS-staged).
__global__ __launch_bounds__(256) void ta_prep_beta(const float* __restrict__ cand,
                                                    const float* __restrict__ W1,
                                                    const float* __restrict__ b1,
                                                    float* __restrict__ beta, int B) {
  __shared__ float w1b[B_D][B_D];   // 64 KB
  const int tid = threadIdx.x;
  #pragma unroll
  for (int i = 0; i < 16; ++i) {
    int v = i * 256 + tid;
    ((f32x4*)w1b)[v] = ((const f32x4*)(W1 + 128 * B_D))[v];
  }
  __syncthreads();
  const int j = tid & 127, which = tid >> 7;
  const int b0 = blockIdx.x * 8;
  #pragma unroll
  for (int bi = 0; bi < 4; ++bi) {
    int b = b0 + bi * 2 + which;
    if (b < B) {
      const float* cb = cand + (size_t)b * B_D;
      float s0 = b1[j], s1 = 0.f, s2 = 0.f, s3 = 0.f;
      #pragma unroll 8
      for (int k = 0; k < 128; k += 4) {
        s0 = fmaf(cb[k    ], w1b[k    ][j], s0);
        s1 = fmaf(cb[k + 1], w1b[k + 1][j], s1);
        s2 = fmaf(cb[k + 2], w1b[k + 2][j], s2);
        s3 = fmaf(cb[k + 3], w1b[k + 3][j], s3);
      }
      beta[(size_t)b * B_D + j] = (s0 + s1) + (s2 + s3);
    }
  }
}

// ---- main: 256 threads / 4 waves. NO min-blocks arg: with (…,4) the
// compiler pins VGPR=64 and spills (R1/R3/R12); natural allocation (~95-110)
// gives 3-4 waves/SIMD by HW limits with zero spill.
__global__ __launch_bounds__(256)
void ta_fused(const float* __restrict__ x,      // [B,T,D]
              const float* __restrict__ cand,   // [B,D]
              const void*  __restrict__ maskp,  // [B,T] int32 or 1-byte bool
              const float* __restrict__ W1,     // [384,128]
              const float* __restrict__ b1,     // [128]
              const float* __restrict__ ap,     // [1]
              const float* __restrict__ W2,     // [128]
              const short* __restrict__ wfrag,  // [2][2048] bf16 octets (prep)
              const float* __restrict__ beta,   // [B,128] (prep)
              int use_ws,
              float* __restrict__ out)          // [B,D]
{
  // wbt fragment-linear bf16; dead after the last MFMA -> part aliases it.
  __shared__ __align__(16) short wbt[B_D * B_D];   // 32 KB
  __shared__ float bpart[2][B_D];                  // fallback beta halves
  __shared__ float red[8];
  float (*part)[B_D] = (float (*)[B_D])wbt;

  const int b    = blockIdx.x;
  const int tid  = threadIdx.x;
  const int lane = tid & 63;
  const int wv   = tid >> 6;      // 0..3
  const int l15  = lane & 15;
  const int g    = lane >> 4;     // 0..3

  // ---- mask dtype probe (same 512B on every wave -> block-consistent)
  int flag1b;
  {
    const unsigned char* mb = (const unsigned char*)maskp;
    unsigned long long v8 = *(const unsigned long long*)(mb + lane * 8);
    flag1b = __any((v8 & 0xFFFFFF00FFFFFF00ull) != 0ull);
  }
  // per-wave row masks for its tiles (row = MT*16 + l15)
  const unsigned char* mb8 = (const unsigned char*)maskp;
  const int* mb32 = (const int*)maskp;
  #define LDMK(ROW) (flag1b ? (mb8[(size_t)b * B_T + (ROW)] != 0) \
                            : (mb32[(size_t)b * B_T + (ROW)] != 0))
  const bool mk0 = LDMK(wv * 16 + l15);
  const bool mk1 = LDMK((4 + wv) * 16 + l15);
  const bool mk2 = LDMK((8 + wv) * 16 + l15);
  const bool mk3 = (wv == 0) ? LDMK(192 + l15 < B_T ? 192 + l15 : B_T - 1) : false;
  #undef LDMK

  // ---- phase 1: Wb -> wbt (prep tables when available)
  const float* cb = cand + (size_t)b * B_D;
  if (use_ws) {
    #pragma unroll 2
    for (int it = 0; it < 8; ++it) {
      const int o = it * 256 + tid;       // o = ko*128 + j
      const int k0 = (o >> 7) * 8;        // wave-uniform
      short8 wa = *(const short8*)&wfrag[o * 8];
      short8 wc = *(const short8*)&wfrag[16384 + o * 8];
      short8 t;
      #pragma unroll
      for (int e = 0; e < 8; ++e)
        t[e] = f2bf(fmaf(cb[k0 + e], bf2f(wc[e]), bf2f(wa[e])));
      *(short8*)&wbt[o * 8] = t;
    }
  } else {
    const int j = tid & 127, h = tid >> 7;
    #pragma unroll 2
    for (int it = 0; it < 8; ++it) {
      const int ko = it * 2 + h, k0 = ko * 8;
      short8 t;
      #pragma unroll
      for (int e = 0; e < 8; ++e) {
        float c  = cb[k0 + e];
        float wa = W1[(size_t)(k0 + e) * B_D + j];
        float wc = W1[(size_t)(256 + k0 + e) * B_D + j];
        t[e] = f2bf(fmaf(c, wc, wa));
      }
      *(short8*)&wbt[(ko * B_D + j) * 8] = t;
    }
    float s0 = (h == 0) ? b1[j] : 0.f, s1 = 0.f, s2 = 0.f, s3 = 0.f;
    const float* w1b = W1 + (size_t)(B_D + h * 64) * B_D + j;
    #pragma unroll 8
    for (int k = 0; k < 64; k += 4) {
      s0 = fmaf(cb[h * 64 + k    ], w1b[(size_t)(k    ) * B_D], s0);
      s1 = fmaf(cb[h * 64 + k + 1], w1b[(size_t)(k + 1) * B_D], s1);
      s2 = fmaf(cb[h * 64 + k + 2], w1b[(size_t)(k + 2) * B_D], s2);
      s3 = fmaf(cb[h * 64 + k + 3], w1b[(size_t)(k + 3) * B_D], s3);
    }
    bpart[h][j] = (s0 + s1) + (s2 + s3);
  }
  __syncthreads();   // barrier 1 (only one before MFMA)

  float betaL[8], w2L[8];
  #pragma unroll
  for (int nt = 0; nt < 8; ++nt) {
    int col = nt * 16 + l15;
    betaL[nt] = use_ws ? beta[(size_t)b * B_D + col] : (bpart[0][col] + bpart[1][col]);
    w2L[nt]   = W2[col];
  }
  const float alpha = ap[0];

  // ---- online state
  float m = -INFINITY, Z = 0.f;
  float O[32];
  #pragma unroll
  for (int i = 0; i < 32; ++i) O[i] = 0.f;

  // ---- fused tile: load -> MFMA -> scores -> online softmax -> O += e*x
  // O accumulates from the bf16 frags (a0..a3) so the f32 staging regs die
  // at cvt8 (-32 VGPR demand). bf16-sourced output proven at 1.95e-3 (R1/R2).
#define TILE_ONLINE(MT, MKV) do {                                             \
    const int rowi = (MT) * 16 + l15;                                         \
    const bool rv = rowi < B_T;                                               \
    const int rowc = rv ? rowi : (B_T - 1);                                   \
    const float* xr = x + ((size_t)b * B_T + rowc) * B_D + g * 8;             \
    f32x4 p0 = *(const f32x4*)(xr +  0), p1 = *(const f32x4*)(xr +   4);      \
    f32x4 p2 = *(const f32x4*)(xr + 32), p3 = *(const f32x4*)(xr +  36);      \
    f32x4 p4 = *(const f32x4*)(xr + 64), p5 = *(const f32x4*)(xr +  68);      \
    f32x4 p6 = *(const f32x4*)(xr + 96), p7 = *(const f32x4*)(xr + 100);      \
    short8 a0 = cvt8(p0, p1), a1 = cvt8(p2, p3);                              \
    short8 a2 = cvt8(p4, p5), a3 = cvt8(p6, p7);                              \
    float sc[4] = {0.f, 0.f, 0.f, 0.f};                                       \
    _Pragma("unroll")                                                         \
    for (int nt = 0; nt < 8; ++nt) {                                          \
      f32x4 acc = {0.f, 0.f, 0.f, 0.f};                                       \
      const short8* wp = (const short8*)wbt + g * B_D + nt * 16 + l15;        \
      acc = __builtin_amdgcn_mfma_f32_16x16x32_bf16(a0, wp[0],    acc, 0,0,0);\
      acc = __builtin_amdgcn_mfma_f32_16x16x32_bf16(a1, wp[512],  acc, 0,0,0);\
      acc = __builtin_amdgcn_mfma_f32_16x16x32_bf16(a2, wp[1024], acc, 0,0,0);\
      acc = __builtin_amdgcn_mfma_f32_16x16x32_bf16(a3, wp[1536], acc, 0,0,0);\
      _Pragma("unroll")                                                       \
      for (int r = 0; r < 4; ++r) {                                           \
        float h = acc[r] + betaL[nt];                                         \
        float p = (h >= 0.f) ? h : alpha * h;                                 \
        sc[r] += p * w2L[nt];                                                 \
      }                                                                       \
    }                                                                         \
    _Pragma("unroll")                                                         \
    for (int r = 0; r < 4; ++r) {                                             \
      sc[r] += __shfl_xor(sc[r], 1, 16); sc[r] += __shfl_xor(sc[r], 2, 16);   \
      sc[r] += __shfl_xor(sc[r], 4, 16); sc[r] += __shfl_xor(sc[r], 8, 16);   \
    }                                                                         \
    float tmax = fmaxf(fmaxf(sc[0], sc[1]), fmaxf(sc[2], sc[3]));             \
    tmax = fmaxf(tmax, __shfl_xor(tmax, 16, 64));                             \
    tmax = fmaxf(tmax, __shfl_xor(tmax, 32, 64));                             \
    if (tmax > m) {   /* wave-uniform */                                      \
      float rs = __expf(m - tmax); m = tmax; Z *= rs;                         \
      _Pragma("unroll") for (int i2 = 0; i2 < 32; ++i2) O[i2] *= rs;          \
    }                                                                         \
    float vsel = sc[0];                                                       \
    vsel = ((l15 & 3) == 1) ? sc[1] : vsel;                                   \
    vsel = ((l15 & 3) == 2) ? sc[2] : vsel;                                   \
    vsel = ((l15 & 3) == 3) ? sc[3] : vsel;                                   \
    float srow = __shfl(vsel, (l15 >> 2) * 16 + l15, 64);                     \
    float ew = (rv && (MKV)) ? __expf(srow - m) : 0.f;                        \
    float ts = ew;                                                            \
    ts += __shfl_xor(ts, 1, 16); ts += __shfl_xor(ts, 2, 16);                 \
    ts += __shfl_xor(ts, 4, 16); ts += __shfl_xor(ts, 8, 16);                 \
    Z += ts;                                                                  \
    _Pragma("unroll")                                                         \
    for (int e2 = 0; e2 < 8; ++e2) {                                          \
      O[ 0 + e2] = fmaf(ew, bf2f(a0[e2]), O[ 0 + e2]);                        \
      O[ 8 + e2] = fmaf(ew, bf2f(a1[e2]), O[ 8 + e2]);                        \
      O[16 + e2] = fmaf(ew, bf2f(a2[e2]), O[16 + e2]);                        \
      O[24 + e2] = fmaf(ew, bf2f(a3[e2]), O[24 + e2]);                        \
    }                                                                         \
  } while (0)

  TILE_ONLINE(wv, mk0);
  TILE_ONLINE(4 + wv, mk1);
  TILE_ONLINE(8 + wv, mk2);
  if (wv == 0) TILE_ONLINE(12, mk3);
#undef TILE_ONLINE

  // ---- cross-wave m/Z combine
  if (lane == 0) { red[wv] = m; red[4 + wv] = Z; }
  __syncthreads();   // barrier 2; wbt dead after this -> part alias OK
  float mg = fmaxf(fmaxf(red[0], red[1]), fmaxf(red[2], red[3]));
  float Zg = red[4] * __expf(red[0] - mg) + red[5] * __expf(red[1] - mg)
           + red[6] * __expf(red[2] - mg) + red[7] * __expf(red[3] - mg);
  const float fac = __expf(m - mg) / Zg;

  // ---- row-reduce O over l15 (butterfly)
  #pragma unroll
  for (int i = 0; i < 32; ++i) {
    float v = O[i] * fac;
    v += __shfl_xor(v, 1, 16); v += __shfl_xor(v, 2, 16);
    v += __shfl_xor(v, 4, 16); v += __shfl_xor(v, 8, 16);
    O[i] = v;
  }
  // O[i] (i = ks*8+e) is out element d = (i>>3)*32 + g*8 + (i&7), per wave.
  if (l15 == 0) {
    #pragma unroll
    for (int i = 0; i < 32; ++i)
      part[wv][(i >> 3) * 32 + g * 8 + (i & 7)] = O[i];
  }
  __syncthreads();   // barrier 3
  if (tid < B_D) {
    out[(size_t)b * B_D + tid] =
        (part[0][tid] + part[1][tid]) + (part[2][tid] + part[3][tid]);
  }
}

extern "C" void kernel_launch(void* const* d_in, const int* in_sizes, int n_in,
                              void* d_out, int out_size, void* d_ws, size_t ws_size,
                              hipStream_t stream) {
  const float* x    = (const float*)d_in[0];
  const float* cand = (const float*)d_in[1];
  const void*  mask = d_in[2];
  const float* W1   = (const float*)d_in[3];
  const float* b1   = (const float*)d_in[4];
  const float* a    = (const float*)d_in[5];
  const float* W2   = (const float*)d_in[6];
  float* out = (float*)d_out;
  const int B = in_sizes[1] / B_D;   // candidate is [B,128]

  short* wfrag = (short*)d_ws;                       // 64 KB
  float* beta  = (float*)((char*)d_ws + 65536);      // B*128 f32
  const size_t need = 65536 + (size_t)B * B_D * sizeof(float);
  const int use_ws = (ws_size >= need) ? 1 : 0;

  if (use_ws) {
    ta_prep_w<<<8, 256, 0, stream>>>(W1, wfrag);
    ta_prep_beta<<<(B + 7) / 8, 256, 0, stream>>>(cand, W1, b1, beta, B);
  }
  ta_fused<<<B, 256, 0, stream>>>(x, cand, mask, W1, b1, a, W2,
                                  wfrag, beta, use_ws, out);
}

// Round 14
// 232.984 us; speedup vs baseline: 1.1815x; 1.1815x over previous
//
#include <hip/hip_runtime.h>
#include <hip/hip_bf16.h>

typedef __attribute__((ext_vector_type(8))) short short8;
typedef __attribute__((ext_vector_type(4))) float f32x4;

#define B_T 200
#define B_D 128

static __device__ __forceinline__ short f2bf(float f) {
  // round-to-nearest-even f32 -> bf16 (inputs are finite)
  unsigned u = __builtin_bit_cast(unsigned, f);
  u += 0x7fffu + ((u >> 16) & 1u);
  return (short)(u >> 16);
}
static __device__ __forceinline__ float bf2f(short s) {
  unsigned u = ((unsigned)(unsigned short)s) << 16;
  return __builtin_bit_cast(float, u);
}
static __device__ __forceinline__ short8 cvt8(f32x4 a, f32x4 b) {
  short8 t;
  t[0] = f2bf(a[0]); t[1] = f2bf(a[1]); t[2] = f2bf(a[2]); t[3] = f2bf(a[3]);
  t[4] = f2bf(b[0]); t[5] = f2bf(b[1]); t[6] = f2bf(b[2]); t[7] = f2bf(b[3]);
  return t;
}

// ---- prep 1: W1a/W1c -> fragment-linear bf16 tables (block-invariant, once).
__global__ __launch_bounds__(256) void ta_prep_w(const float* __restrict__ W1,
                                                 short* __restrict__ wfrag) {
  const int o = blockIdx.x * 256 + threadIdx.x;   // 2048 octets
  const int j = o & 127, k0 = (o >> 7) * 8;
  short8 ta, tc;
  #pragma unroll
  for (int e = 0; e < 8; ++e) {
    ta[e] = f2bf(W1[(size_t)(k0 + e) * B_D + j]);
    tc[e] = f2bf(W1[(size_t)(256 + k0 + e) * B_D + j]);
  }
  *(short8*)&wfrag[o * 8] = ta;
  *(short8*)&wfrag[16384 + o * 8] = tc;
}

// ---- prep 2: beta[b][j] = b1[j] + sum_k c[b][k]*W1b[k][j] (W1b LDS-staged).
__global__ __launch_bounds__(256) void ta_prep_beta(const float* __restrict__ cand,
                                                    const float* __restrict__ W1,
                                                    const float* __restrict__ b1,
                                                    float* __restrict__ beta, int B) {
  __shared__ float w1b[B_D][B_D];   // 64 KB
  const int tid = threadIdx.x;
  #pragma unroll
  for (int i = 0; i < 16; ++i) {
    int v = i * 256 + tid;
    ((f32x4*)w1b)[v] = ((const f32x4*)(W1 + 128 * B_D))[v];
  }
  __syncthreads();
  const int j = tid & 127, which = tid >> 7;
  const int b0 = blockIdx.x * 8;
  #pragma unroll
  for (int bi = 0; bi < 4; ++bi) {
    int b = b0 + bi * 2 + which;
    if (b < B) {
      const float* cb = cand + (size_t)b * B_D;
      float s0 = b1[j], s1 = 0.f, s2 = 0.f, s3 = 0.f;
      #pragma unroll 8
      for (int k = 0; k < 128; k += 4) {
        s0 = fmaf(cb[k    ], w1b[k    ][j], s0);
        s1 = fmaf(cb[k + 1], w1b[k + 1][j], s1);
        s2 = fmaf(cb[k + 2], w1b[k + 2][j], s2);
        s3 = fmaf(cb[k + 3], w1b[k + 3][j], s3);
      }
      beta[(size_t)b * B_D + j] = (s0 + s1) + (s2 + s3);
    }
  }
}

// ---- main: 256 threads / 4 waves, __launch_bounds__(256, 3):
// total-reg cap 170/wave (demand ~150 -> NO spill to scratch OR AGPR-balloon),
// waves-per-EU clamp = 3 -> 12 waves/CU = 3 resident blocks/CU.
// [R13: unbounded -> 132V + AGPR balloon -> 1 wave/EU, 284us.
//  R12: (…,4) -> 64V cap -> scratch spill, 246us.]
__global__ __launch_bounds__(256, 3)
void ta_fused(const float* __restrict__ x,      // [B,T,D]
              const float* __restrict__ cand,   // [B,D]
              const void*  __restrict__ maskp,  // [B,T] int32 or 1-byte bool
              const float* __restrict__ W1,     // [384,128]
              const float* __restrict__ b1,     // [128]
              const float* __restrict__ ap,     // [1]
              const float* __restrict__ W2,     // [128]
              const short* __restrict__ wfrag,  // [2][2048] bf16 octets (prep)
              const float* __restrict__ beta,   // [B,128] (prep)
              int use_ws,
              float* __restrict__ out)          // [B,D]
{
  // wbt fragment-linear bf16; dead after the last MFMA -> part aliases it.
  __shared__ __align__(16) short wbt[B_D * B_D];   // 32 KB
  __shared__ float bpart[2][B_D];                  // fallback beta halves
  __shared__ float red[8];
  float (*part)[B_D] = (float (*)[B_D])wbt;

  const int b    = blockIdx.x;
  const int tid  = threadIdx.x;
  const int lane = tid & 63;
  const int wv   = tid >> 6;      // 0..3
  const int l15  = lane & 15;
  const int g    = lane >> 4;     // 0..3

  // ---- mask dtype probe (same 512B on every wave -> block-consistent)
  int flag1b;
  {
    const unsigned char* mb = (const unsigned char*)maskp;
    unsigned long long v8 = *(const unsigned long long*)(mb + lane * 8);
    flag1b = __any((v8 & 0xFFFFFF00FFFFFF00ull) != 0ull);
  }
  // per-wave row masks for its tiles (row = MT*16 + l15)
  const unsigned char* mb8 = (const unsigned char*)maskp;
  const int* mb32 = (const int*)maskp;
  #define LDMK(ROW) (flag1b ? (mb8[(size_t)b * B_T + (ROW)] != 0) \
                            : (mb32[(size_t)b * B_T + (ROW)] != 0))
  const bool mk0 = LDMK(wv * 16 + l15);
  const bool mk1 = LDMK((4 + wv) * 16 + l15);
  const bool mk2 = LDMK((8 + wv) * 16 + l15);
  const bool mk3 = (wv == 0) ? LDMK(192 + l15 < B_T ? 192 + l15 : B_T - 1) : false;
  #undef LDMK

  // ---- phase 1: Wb -> wbt (prep tables when available)
  const float* cb = cand + (size_t)b * B_D;
  if (use_ws) {
    #pragma unroll 2
    for (int it = 0; it < 8; ++it) {
      const int o = it * 256 + tid;       // o = ko*128 + j
      const int k0 = (o >> 7) * 8;        // wave-uniform
      short8 wa = *(const short8*)&wfrag[o * 8];
      short8 wc = *(const short8*)&wfrag[16384 + o * 8];
      short8 t;
      #pragma unroll
      for (int e = 0; e < 8; ++e)
        t[e] = f2bf(fmaf(cb[k0 + e], bf2f(wc[e]), bf2f(wa[e])));
      *(short8*)&wbt[o * 8] = t;
    }
  } else {
    const int j = tid & 127, h = tid >> 7;
    #pragma unroll 2
    for (int it = 0; it < 8; ++it) {
      const int ko = it * 2 + h, k0 = ko * 8;
      short8 t;
      #pragma unroll
      for (int e = 0; e < 8; ++e) {
        float c  = cb[k0 + e];
        float wa = W1[(size_t)(k0 + e) * B_D + j];
        float wc = W1[(size_t)(256 + k0 + e) * B_D + j];
        t[e] = f2bf(fmaf(c, wc, wa));
      }
      *(short8*)&wbt[(ko * B_D + j) * 8] = t;
    }
    float s0 = (h == 0) ? b1[j] : 0.f, s1 = 0.f, s2 = 0.f, s3 = 0.f;
    const float* w1b = W1 + (size_t)(B_D + h * 64) * B_D + j;
    #pragma unroll 8
    for (int k = 0; k < 64; k += 4) {
      s0 = fmaf(cb[h * 64 + k    ], w1b[(size_t)(k    ) * B_D], s0);
      s1 = fmaf(cb[h * 64 + k + 1], w1b[(size_t)(k + 1) * B_D], s1);
      s2 = fmaf(cb[h * 64 + k + 2], w1b[(size_t)(k + 2) * B_D], s2);
      s3 = fmaf(cb[h * 64 + k + 3], w1b[(size_t)(k + 3) * B_D], s3);
    }
    bpart[h][j] = (s0 + s1) + (s2 + s3);
  }
  __syncthreads();   // barrier 1 (only one before MFMA)

  float betaL[8], w2L[8];
  #pragma unroll
  for (int nt = 0; nt < 8; ++nt) {
    int col = nt * 16 + l15;
    betaL[nt] = use_ws ? beta[(size_t)b * B_D + col] : (bpart[0][col] + bpart[1][col]);
    w2L[nt]   = W2[col];
  }
  const float alpha = ap[0];

  // ---- online state
  float m = -INFINITY, Z = 0.f;
  float O[32];
  #pragma unroll
  for (int i = 0; i < 32; ++i) O[i] = 0.f;

  // ---- fused tile: load -> MFMA -> scores -> online softmax -> O += e*x
  // O accumulates from the bf16 frags (a0..a3) so the f32 staging regs die
  // at cvt8. bf16-sourced output proven at absmax 1.95e-3 (R1/R2).
#define TILE_ONLINE(MT, MKV) do {                                             \
    const int rowi = (MT) * 16 + l15;                                         \
    const bool rv = rowi < B_T;                                               \
    const int rowc = rv ? rowi : (B_T - 1);                                   \
    const float* xr = x + ((size_t)b * B_T + rowc) * B_D + g * 8;             \
    f32x4 p0 = *(const f32x4*)(xr +  0), p1 = *(const f32x4*)(xr +   4);      \
    f32x4 p2 = *(const f32x4*)(xr + 32), p3 = *(const f32x4*)(xr +  36);      \
    f32x4 p4 = *(const f32x4*)(xr + 64), p5 = *(const f32x4*)(xr +  68);      \
    f32x4 p6 = *(const f32x4*)(xr + 96), p7 = *(const f32x4*)(xr + 100);      \
    short8 a0 = cvt8(p0, p1), a1 = cvt8(p2, p3);                              \
    short8 a2 = cvt8(p4, p5), a3 = cvt8(p6, p7);                              \
    float sc[4] = {0.f, 0.f, 0.f, 0.f};                                       \
    _Pragma("unroll")                                                         \
    for (int nt = 0; nt < 8; ++nt) {                                          \
      f32x4 acc = {0.f, 0.f, 0.f, 0.f};                                       \
      const short8* wp = (const short8*)wbt + g * B_D + nt * 16 + l15;        \
      acc = __builtin_amdgcn_mfma_f32_16x16x32_bf16(a0, wp[0],    acc, 0,0,0);\
      acc = __builtin_amdgcn_mfma_f32_16x16x32_bf16(a1, wp[512],  acc, 0,0,0);\
      acc = __builtin_amdgcn_mfma_f32_16x16x32_bf16(a2, wp[1024], acc, 0,0,0);\
      acc = __builtin_amdgcn_mfma_f32_16x16x32_bf16(a3, wp[1536], acc, 0,0,0);\
      _Pragma("unroll")                                                       \
      for (int r = 0; r < 4; ++r) {                                           \
        float h = acc[r] + betaL[nt];                                         \
        float p = (h >= 0.f) ? h : alpha * h;                                 \
        sc[r] += p * w2L[nt];                                                 \
      }                                                                       \
    }                                                                         \
    _Pragma("unroll")                                                         \
    for (int r = 0; r < 4; ++r) {                                             \
      sc[r] += __shfl_xor(sc[r], 1, 16); sc[r] += __shfl_xor(sc[r], 2, 16);   \
      sc[r] += __shfl_xor(sc[r], 4, 16); sc[r] += __shfl_xor(sc[r], 8, 16);   \
    }                                                                         \
    float tmax = fmaxf(fmaxf(sc[0], sc[1]), fmaxf(sc[2], sc[3]));             \
    tmax = fmaxf(tmax, __shfl_xor(tmax, 16, 64));                             \
    tmax = fmaxf(tmax, __shfl_xor(tmax, 32, 64));                             \
    if (tmax > m) {   /* wave-uniform */                                      \
      float rs = __expf(m - tmax); m = tmax; Z *= rs;                         \
      _Pragma("unroll") for (int i2 = 0; i2 < 32; ++i2) O[i2] *= rs;          \
    }                                                                         \
    float vsel = sc[0];                                                       \
    vsel = ((l15 & 3) == 1) ? sc[1] : vsel;                                   \
    vsel = ((l15 & 3) == 2) ? sc[2] : vsel;                                   \
    vsel = ((l15 & 3) == 3) ? sc[3] : vsel;                                   \
    float srow = __shfl(vsel, (l15 >> 2) * 16 + l15, 64);                     \
    float ew = (rv && (MKV)) ? __expf(srow - m) : 0.f;                        \
    float ts = ew;                                                            \
    ts += __shfl_xor(ts, 1, 16); ts += __shfl_xor(ts, 2, 16);                 \
    ts += __shfl_xor(ts, 4, 16); ts += __shfl_xor(ts, 8, 16);                 \
    Z += ts;                                                                  \
    _Pragma("unroll")                                                         \
    for (int e2 = 0; e2 < 8; ++e2) {                                          \
      O[ 0 + e2] = fmaf(ew, bf2f(a0[e2]), O[ 0 + e2]);                        \
      O[ 8 + e2] = fmaf(ew, bf2f(a1[e2]), O[ 8 + e2]);                        \
      O[16 + e2] = fmaf(ew, bf2f(a2[e2]), O[16 + e2]);                        \
      O[24 + e2] = fmaf(ew, bf2f(a3[e2]), O[24 + e2]);                        \
    }                                                                         \
  } while (0)

  TILE_ONLINE(wv, mk0);
  TILE_ONLINE(4 + wv, mk1);
  TILE_ONLINE(8 + wv, mk2);
  if (wv == 0) TILE_ONLINE(12, mk3);
#undef TILE_ONLINE

  // ---- cross-wave m/Z combine
  if (lane == 0) { red[wv] = m; red[4 + wv] = Z; }
  __syncthreads();   // barrier 2; wbt dead after this -> part alias OK
  float mg = fmaxf(fmaxf(red[0], red[1]), fmaxf(red[2], red[3]));
  float Zg = red[4] * __expf(red[0] - mg) + red[5] * __expf(red[1] - mg)
           + red[6] * __expf(red[2] - mg) + red[7] * __expf(red[3] - mg);
  const float fac = __expf(m - mg) / Zg;

  // ---- row-reduce O over l15 (butterfly)
  #pragma unroll
  for (int i = 0; i < 32; ++i) {
    float v = O[i] * fac;
    v += __shfl_xor(v, 1, 16); v += __shfl_xor(v, 2, 16);
    v += __shfl_xor(v, 4, 16); v += __shfl_xor(v, 8, 16);
    O[i] = v;
  }
  // O[i] (i = ks*8+e) is out element d = (i>>3)*32 + g*8 + (i&7), per wave.
  if (l15 == 0) {
    #pragma unroll
    for (int i = 0; i < 32; ++i)
      part[wv][(i >> 3) * 32 + g * 8 + (i & 7)] = O[i];
  }
  __syncthreads();   // barrier 3
  if (tid < B_D) {
    out[(size_t)b * B_D + tid] =
        (part[0][tid] + part[1][tid]) + (part[2][tid] + part[3][tid]);
  }
}

extern "C" void kernel_launch(void* const* d_in, const int* in_sizes, int n_in,
                              void* d_out, int out_size, void* d_ws, size_t ws_size,
                              hipStream_t stream) {
  const float* x    = (const float*)d_in[0];
  const float* cand = (const float*)d_in[1];
  const void*  mask = d_in[2];
  const float* W1   = (const float*)d_in[3];
  const float* b1   = (const float*)d_in[4];
  const float* a    = (const float*)d_in[5];
  const float* W2   = (const float*)d_in[6];
  float* out = (float*)d_out;
  const int B = in_sizes[1] / B_D;   // candidate is [B,128]

  short* wfrag = (short*)d_ws;                       // 64 KB
  float* beta  = (float*)((char*)d_ws + 65536);      // B*128 f32
  const size_t need = 65536 + (size_t)B * B_D * sizeof(float);
  const int use_ws = (ws_size >= need) ? 1 : 0;

  if (use_ws) {
    ta_prep_w<<<8, 256, 0, stream>>>(W1, wfrag);
    ta_prep_beta<<<(B + 7) / 8, 256, 0, stream>>>(cand, W1, b1, beta, B);
  }
  ta_fused<<<B, 256, 0, stream>>>(x, cand, mask, W1, b1, a, W2,
                                  wfrag, beta, use_ws, out);
}

// Round 15
// 147.546 us; speedup vs baseline: 1.8657x; 1.5791x over previous
//
#include <hip/hip_runtime.h>
#include <hip/hip_bf16.h>

typedef __attribute__((ext_vector_type(8))) short short8;
typedef __attribute__((ext_vector_type(4))) float f32x4;

#define B_T 200
#define B_D 128

static __device__ __forceinline__ short f2bf(float f) {
  // round-to-nearest-even f32 -> bf16 (inputs are finite)
  unsigned u = __builtin_bit_cast(unsigned, f);
  u += 0x7fffu + ((u >> 16) & 1u);
  return (short)(u >> 16);
}
static __device__ __forceinline__ short8 cvt8(f32x4 a, f32x4 b) {
  short8 t;
  t[0] = f2bf(a[0]); t[1] = f2bf(a[1]); t[2] = f2bf(a[2]); t[3] = f2bf(a[3]);
  t[4] = f2bf(b[0]); t[5] = f2bf(b[1]); t[6] = f2bf(b[2]); t[7] = f2bf(b[3]);
  return t;
}

// 256 threads / 4 waves. amdgpu_waves_per_eu(4,4): EXACTLY 4 waves/EU ->
// 128-reg/wave budget, allocator neither aims for 8 waves (64-cap scratch
// spill: R1/R2/R12) nor balloons into AGPRs past the cap (R13/R14).
// 16 waves/CU = 4 resident blocks (LDS 38 KB x 4 = 153 KB <= 160).
__global__ __launch_bounds__(256)
__attribute__((amdgpu_waves_per_eu(4, 4)))
void ta_fused(const float* __restrict__ x,      // [B,T,D]
              const float* __restrict__ cand,   // [B,D]
              const void*  __restrict__ maskp,  // [B,T] int32 or 1-byte bool
              const float* __restrict__ W1,     // [384,128]
              const float* __restrict__ b1,     // [128]
              const float* __restrict__ ap,     // [1]
              const float* __restrict__ W2,     // [128]
              const float* __restrict__ b2p,    // [1] (unused: softmax shift-invariant)
              float* __restrict__ out)          // [B,D]
{
  // wbt fragment-linear bf16: element (k,j) at ((k>>3)*128 + j)*8 + (k&7).
  __shared__ __align__(16) short wbt[B_D * B_D];   // 32 KB
  __shared__ float part[8][B_D];   // beta halves [0..1]; phase-C partials [0..7]
  __shared__ float scores[208];
  __shared__ float red[8];

  const int b    = blockIdx.x;
  const int tid  = threadIdx.x;
  const int lane = tid & 63;
  const int wv   = tid >> 6;      // 0..3
  const int l15  = lane & 15;
  const int g    = lane >> 4;     // 0..3

  // ---- tile-0 x loads FIRST: latency hides under the whole Wb build.
  // row = wv*16 + l15 <= 63 < 200, always valid.
  const float* xr0p = x + ((size_t)b * B_T + wv * 16 + l15) * B_D + g * 8;
  f32x4 r0 = *(const f32x4*)(xr0p +  0), r1 = *(const f32x4*)(xr0p +   4);
  f32x4 r2 = *(const f32x4*)(xr0p + 32), r3 = *(const f32x4*)(xr0p +  36);
  f32x4 r4 = *(const f32x4*)(xr0p + 64), r5 = *(const f32x4*)(xr0p +  68);
  f32x4 r6 = *(const f32x4*)(xr0p + 96), r7 = *(const f32x4*)(xr0p + 100);

  // ---- mask dtype probe (same 512B on every wave -> block-consistent)
  int flag1b;
  {
    const unsigned char* mb = (const unsigned char*)maskp;
    unsigned long long v8 = *(const unsigned long long*)(mb + lane * 8);
    flag1b = __any((v8 & 0xFFFFFF00FFFFFF00ull) != 0ull);
  }
  bool mk = false;
  if (tid < B_T) {
    if (flag1b) mk = ((const unsigned char*)maskp)[(size_t)b * B_T + tid] != 0;
    else        mk = ((const int*)maskp)[(size_t)b * B_T + tid] != 0;
  }

  // ---- phase 1: Wb = W1a + c (*) W1c -> wbt ; beta halves -> part[0..1]
  const float* cb = cand + (size_t)b * B_D;
  {
    const int j = tid & 127;
    const int h = tid >> 7;           // 0..1 (wave-uniform)
    #pragma unroll 2
    for (int it = 0; it < 8; ++it) {
      const int ko = it * 2 + h, k0 = ko * 8;
      short8 t;
      #pragma unroll
      for (int e = 0; e < 8; ++e) {
        float c  = cb[k0 + e];
        float wa = W1[(size_t)(k0 + e) * B_D + j];
        float wc = W1[(size_t)(256 + k0 + e) * B_D + j];
        t[e] = f2bf(fmaf(c, wc, wa));
      }
      *(short8*)&wbt[(ko * B_D + j) * 8] = t;   // consecutive-lane 16B write
    }
    float s0 = (h == 0) ? b1[j] : 0.f, s1 = 0.f, s2 = 0.f, s3 = 0.f;
    const float* w1b = W1 + (size_t)(B_D + h * 64) * B_D + j;
    #pragma unroll 8
    for (int k = 0; k < 64; k += 4) {
      s0 = fmaf(cb[h * 64 + k    ], w1b[(size_t)(k    ) * B_D], s0);
      s1 = fmaf(cb[h * 64 + k + 1], w1b[(size_t)(k + 1) * B_D], s1);
      s2 = fmaf(cb[h * 64 + k + 2], w1b[(size_t)(k + 2) * B_D], s2);
      s3 = fmaf(cb[h * 64 + k + 3], w1b[(size_t)(k + 3) * B_D], s3);
    }
    part[h][j] = (s0 + s1) + (s2 + s3);
  }
  __syncthreads();   // barrier 1 (only one before MFMA)

  float betaL[8], w2L[8];
  #pragma unroll
  for (int nt = 0; nt < 8; ++nt) {
    int col = nt * 16 + l15;
    betaL[nt] = part[0][col] + part[1][col];
    w2L[nt]   = W2[col];            // L1/L2-hot, no LDS staging needed
  }
  const float alpha = ap[0];

  // ---- phase A: software-pipelined tiles: prefetch k+1 loads before k's MFMAs
#define LOADX(MT_ROW) do {                                                    \
    const float* xp_ = x + ((size_t)b * B_T + (MT_ROW)) * B_D + g * 8;        \
    r0 = *(const f32x4*)(xp_ +  0); r1 = *(const f32x4*)(xp_ +   4);          \
    r2 = *(const f32x4*)(xp_ + 32); r3 = *(const f32x4*)(xp_ +  36);          \
    r4 = *(const f32x4*)(xp_ + 64); r5 = *(const f32x4*)(xp_ +  68);          \
    r6 = *(const f32x4*)(xp_ + 96); r7 = *(const f32x4*)(xp_ + 100);          \
  } while (0)

#define COMPUTE_SCORE(TB) do {                                                \
    float sc[4] = {0.f, 0.f, 0.f, 0.f};                                       \
    _Pragma("unroll")                                                         \
    for (int nt = 0; nt < 8; ++nt) {                                          \
      f32x4 acc = {0.f, 0.f, 0.f, 0.f};                                       \
      const short8* wp = (const short8*)wbt + g * B_D + nt * 16 + l15;        \
      acc = __builtin_amdgcn_mfma_f32_16x16x32_bf16(a0, wp[0],    acc, 0,0,0);\
      acc = __builtin_amdgcn_mfma_f32_16x16x32_bf16(a1, wp[512],  acc, 0,0,0);\
      acc = __builtin_amdgcn_mfma_f32_16x16x32_bf16(a2, wp[1024], acc, 0,0,0);\
      acc = __builtin_amdgcn_mfma_f32_16x16x32_bf16(a3, wp[1536], acc, 0,0,0);\
      _Pragma("unroll")                                                       \
      for (int r = 0; r < 4; ++r) {                                           \
        float h_ = acc[r] + betaL[nt];                                        \
        float p_ = (h_ >= 0.f) ? h_ : alpha * h_;                             \
        sc[r] += p_ * w2L[nt];                                                \
      }                                                                       \
    }                                                                         \
    _Pragma("unroll")                                                         \
    for (int r = 0; r < 4; ++r) {                                             \
      float v = sc[r];                                                        \
      v += __shfl_xor(v, 1, 16); v += __shfl_xor(v, 2, 16);                   \
      v += __shfl_xor(v, 4, 16); v += __shfl_xor(v, 8, 16);                   \
      if (l15 == 0) scores[(TB) + g * 4 + r] = v;                             \
    }                                                                         \
  } while (0)

  short8 a0 = cvt8(r0, r1), a1 = cvt8(r2, r3), a2 = cvt8(r4, r5), a3 = cvt8(r6, r7);
  LOADX((4 + wv) * 16 + l15);                    // rows 64..127+15 < 200
  COMPUTE_SCORE(wv * 16);

  a0 = cvt8(r0, r1); a1 = cvt8(r2, r3); a2 = cvt8(r4, r5); a3 = cvt8(r6, r7);
  LOADX((8 + wv) * 16 + l15);                    // rows <= 191 < 200
  COMPUTE_SCORE((4 + wv) * 16);

  a0 = cvt8(r0, r1); a1 = cvt8(r2, r3); a2 = cvt8(r4, r5); a3 = cvt8(r6, r7);
  if (wv == 0) {
    int row3 = 192 + l15; if (row3 > B_T - 1) row3 = B_T - 1;   // clamp tail
    LOADX(row3);
  }
  COMPUTE_SCORE((8 + wv) * 16);

  if (wv == 0) {
    a0 = cvt8(r0, r1); a1 = cvt8(r2, r3); a2 = cvt8(r4, r5); a3 = cvt8(r6, r7);
    COMPUTE_SCORE(192);
  }
#undef LOADX
#undef COMPUTE_SCORE
  __syncthreads();   // barrier 2

  // ---- phase B: masked softmax, scores <- UNNORMALIZED e; divide by Z at end.
  {
    float s = (tid < B_T && mk) ? scores[tid] : -INFINITY;
    float v = s;
    #pragma unroll
    for (int m = 32; m >= 1; m >>= 1) v = fmaxf(v, __shfl_xor(v, m, 64));
    if (lane == 0) red[wv] = v;
    __syncthreads();                 // barrier 3
    float mx = fmaxf(fmaxf(red[0], red[1]), fmaxf(red[2], red[3]));
    float e = mk ? __expf(s - mx) : 0.f;
    float sv = e;
    #pragma unroll
    for (int m = 32; m >= 1; m >>= 1) sv += __shfl_xor(sv, m, 64);
    if (lane == 0) red[4 + wv] = sv;
    if (tid < 208) scores[tid] = e;  // tid in [200,208): e==0
    __syncthreads();                 // barrier 4
  }

  // ---- phase C: part[p][:] = sum_{t in p-slice} e[t]*x[t,:] (L2/L3-hot).
  // Full unroll, 2 independent accumulators -> ~12 loads in flight.
  {
    const int d4 = (tid & 31) << 2;
    const int p  = tid >> 5;            // 0..7, t in [25p, 25p+25)
    const float* xc = x + ((size_t)b * B_T + p * 25) * B_D + d4;
    f32x4 acc0 = {0.f, 0.f, 0.f, 0.f}, acc1 = {0.f, 0.f, 0.f, 0.f};
    #pragma unroll
    for (int t = 0; t < 24; t += 2) {
      f32x4 xv0 = *(const f32x4*)(xc + (size_t)t * B_D);
      f32x4 xv1 = *(const f32x4*)(xc + (size_t)(t + 1) * B_D);
      float w0 = scores[p * 25 + t];
      float w1 = scores[p * 25 + t + 1];
      acc0[0] = fmaf(w0, xv0[0], acc0[0]); acc1[0] = fmaf(w1, xv1[0], acc1[0]);
      acc0[1] = fmaf(w0, xv0[1], acc0[1]); acc1[1] = fmaf(w1, xv1[1], acc1[1]);
      acc0[2] = fmaf(w0, xv0[2], acc0[2]); acc1[2] = fmaf(w1, xv1[2], acc1[2]);
      acc0[3] = fmaf(w0, xv0[3], acc0[3]); acc1[3] = fmaf(w1, xv1[3], acc1[3]);
    }
    {
      f32x4 xv = *(const f32x4*)(xc + (size_t)24 * B_D);
      float w = scores[p * 25 + 24];
      acc0[0] = fmaf(w, xv[0], acc0[0]); acc0[1] = fmaf(w, xv[1], acc0[1]);
      acc0[2] = fmaf(w, xv[2], acc0[2]); acc0[3] = fmaf(w, xv[3], acc0[3]);
    }
    acc0[0] += acc1[0]; acc0[1] += acc1[1]; acc0[2] += acc1[2]; acc0[3] += acc1[3];
    // part[0..1] (beta) last read before barrier 2 -> safe to overwrite now
    *(f32x4*)&part[p][d4] = acc0;
  }
  __syncthreads();   // barrier 5
  if (tid < B_D) {
    float Z = (red[4] + red[5]) + (red[6] + red[7]);
    float s = 0.f;
    #pragma unroll
    for (int p = 0; p < 8; ++p) s += part[p][tid];
    out[(size_t)b * B_D + tid] = s / Z;
  }
}

extern "C" void kernel_launch(void* const* d_in, const int* in_sizes, int n_in,
                              void* d_out, int out_size, void* d_ws, size_t ws_size,
                              hipStream_t stream) {
  const float* x    = (const float*)d_in[0];
  const float* cand = (const float*)d_in[1];
  const void*  mask = d_in[2];
  const float* W1   = (const float*)d_in[3];
  const float* b1   = (const float*)d_in[4];
  const float* a    = (const float*)d_in[5];
  const float* W2   = (const float*)d_in[6];
  const float* b2   = (const float*)d_in[7];
  float* out = (float*)d_out;
  const int B = in_sizes[1] / B_D;   // candidate is [B,128]
  ta_fused<<<B, 256, 0, stream>>>(x, cand, mask, W1, b1, a, W2, b2, out);
}